// Round 11
// baseline (1210.394 us; speedup 1.0000x reference)
//
#include <hip/hip_runtime.h>
#include <hip/hip_fp16.h>

#define DIM 64
#define NG  16          // num graphs (fixed by problem setup)
#define CPG 8           // edge chunks per graph (build)
#define NPG 4096        // nodes per graph (fixed)
#define FPB 4           // features per gather block
#define ASTR 5          // LDS acc stride (pad: coprime with 32 banks)

// ---------------------------------------------------------------------------
// B1: per-chunk LDS sub-histograms (NG*CPG blocks). No global atomics.
// hsub = src histogram (per chunk), dsub = dst histogram (per chunk).
// ---------------------------------------------------------------------------
__global__ __launch_bounds__(256) void b1_hist(
    const int* __restrict__ src, const int* __restrict__ dst,
    int* __restrict__ hsub, int* __restrict__ dsub, int chunk, int npg)
{
    __shared__ int hs[NPG], hd[NPG];
    const int blk = blockIdx.x;
    const int g = blk / CPG;
    const int t = threadIdx.x;
    const int ebase = blk * chunk;     // chunks are graph-major contiguous
    const int nbase = g * npg;
    for (int i = t; i < npg; i += 256) { hs[i] = 0; hd[i] = 0; }
    __syncthreads();
    for (int e = t; e < chunk; e += 256) {
        atomicAdd(&hs[src[ebase + e] - nbase], 1);
        atomicAdd(&hd[dst[ebase + e] - nbase], 1);
    }
    __syncthreads();
    for (int i = t; i < npg; i += 256) {
        hsub[blk * npg + i] = hs[i];
        dsub[blk * npg + i] = hd[i];
    }
}

// ---------------------------------------------------------------------------
// B2: one block per graph. Sum sub-hists -> norms (ns from src-deg, nd from
// dst-deg); in-block exclusive scan of SRC degrees; in-place prefix over
// chunks turns hsub into absolute per-chunk cursor starts (stable counting
// sort by src).
// ---------------------------------------------------------------------------
__global__ __launch_bounds__(1024) void b2_scan(
    int* __restrict__ hsub, const int* __restrict__ dsub,
    float* __restrict__ ns, float* __restrict__ nd,
    int epg, int npg)
{
    __shared__ int tsum[1024];
    const int g = blockIdx.x;
    const int t = threadIdx.x;
    const int nbase = g * npg;
    const int ebase = g * epg;
    const int i0 = t * 4;

    int stot[4];
#pragma unroll
    for (int r = 0; r < 4; ++r) {
        int i = i0 + r;
        int sd = 0, dd = 0;
        for (int k = 0; k < CPG; ++k) {
            sd += hsub[(g * CPG + k) * npg + i];
            dd += dsub[(g * CPG + k) * npg + i];
        }
        stot[r] = sd;
        ns[nbase + i] = sd > 0 ? rsqrtf((float)sd) : 0.0f;
        nd[nbase + i] = dd > 0 ? rsqrtf((float)dd) : 0.0f;
    }
    int s4 = stot[0] + stot[1] + stot[2] + stot[3];
    tsum[t] = s4;
    __syncthreads();
    for (int off = 1; off < 1024; off <<= 1) {
        int x = (t >= off) ? tsum[t - off] : 0;
        __syncthreads();
        tsum[t] += x;
        __syncthreads();
    }
    int c = ebase + (tsum[t] - s4);
#pragma unroll
    for (int r = 0; r < 4; ++r) {
        int i = i0 + r;
        int cc = c;
        for (int k = 0; k < CPG; ++k) {
            int* p = &hsub[(g * CPG + k) * npg + i];
            int old = *p; *p = cc; cc += old;
        }
        c += stot[r];
    }
}

// ---------------------------------------------------------------------------
// B3: counting-sort fill by SRC. epack[pos] = sloc | (dloc << 16).
// LDS cursors init from per-chunk starts. No global atomics.
// ---------------------------------------------------------------------------
__global__ __launch_bounds__(256) void b3_fill(
    const int* __restrict__ src, const int* __restrict__ dst,
    const int* __restrict__ hsub, unsigned int* __restrict__ epack,
    int chunk, int npg)
{
    __shared__ int cur[NPG];
    const int blk = blockIdx.x;
    const int g = blk / CPG;
    const int t = threadIdx.x;
    const int ebase = blk * chunk;
    const int nbase = g * npg;
    for (int i = t; i < npg; i += 256) cur[i] = hsub[blk * npg + i];
    __syncthreads();
    for (int e = t; e < chunk; e += 256) {
        int s = src[ebase + e] - nbase;
        int d = dst[ebase + e] - nbase;
        int pos = atomicAdd(&cur[s], 1);
        epack[pos] = (unsigned int)s | ((unsigned int)d << 16);
    }
}

// ---------------------------------------------------------------------------
// GEMM: out[row,:] = fp16( (in[row,:]*alpha + beta*bprev) @ W )
//   has_prev=0: alpha=ns[row]               (layer 1)
//   has_prev=1: alpha=ns[row]*nd[row], beta=ns[row]  (folds prev epilogue)
// swiz=1: XCD-affine remap (graph g -> XCD g%8).
// ---------------------------------------------------------------------------
#define LSTR 68
__global__ __launch_bounds__(256) void gemm_kernel(
    const float* __restrict__ in, const float* __restrict__ W,
    const float* __restrict__ bprev,
    const float* __restrict__ ns, const float* __restrict__ nd,
    __half* __restrict__ out, int has_prev, int swiz)
{
    __shared__ float Wt[64 * LSTR];   // Wt[c][k]
    __shared__ float xs[32 * LSTR];   // xs[r][k]
    const int tid = threadIdx.x;
    int blk = blockIdx.x;
    if (swiz) {                        // 2048 blocks: 16 graphs x 128
        int x = blk & 7;
        int j = blk >> 3;
        int g = x + ((j >> 7) << 3);
        blk = (g << 7) + (j & 127);
    }
    const int row0 = blk * 32;

    for (int i = tid; i < 64 * 64; i += 256) {
        int k = i >> 6, c = i & 63;
        Wt[c * LSTR + k] = W[i];
    }
    for (int i = tid; i < 32 * 64; i += 256) {
        int r = i >> 6, c = i & 63;
        int row = row0 + r;
        float s = ns[row];
        float a = has_prev ? s * nd[row] : s;
        float bc = has_prev ? s : 0.0f;
        xs[r * LSTR + c] = in[row * 64 + c] * a + bc * bprev[c];
    }
    __syncthreads();

    const int c0 = tid & 31;
    const int r0 = tid >> 5;
    float acc[4][2] = {};
#pragma unroll
    for (int k = 0; k < 64; k += 4) {
        float4 w0 = *(const float4*)&Wt[(c0     ) * LSTR + k];
        float4 w1 = *(const float4*)&Wt[(c0 + 32) * LSTR + k];
#pragma unroll
        for (int rr = 0; rr < 4; ++rr) {
            float4 xv = *(const float4*)&xs[(r0 + 8 * rr) * LSTR + k];
            acc[rr][0] += xv.x * w0.x + xv.y * w0.y + xv.z * w0.z + xv.w * w0.w;
            acc[rr][1] += xv.x * w1.x + xv.y * w1.y + xv.z * w1.z + xv.w * w1.w;
        }
    }
#pragma unroll
    for (int rr = 0; rr < 4; ++rr) {
        int row = row0 + r0 + 8 * rr;
        out[row * 64 + c0     ] = __float2half_rn(acc[rr][0]);
        out[row * 64 + c0 + 32] = __float2half_rn(acc[rr][1]);
    }
}

// ---------------------------------------------------------------------------
// Gather v3: src-ordered edge stream + LDS destination accumulator.
// 256 blocks = (graph, 4-feature slice); block streams ALL of its graph's
// edges (sorted by src -> consecutive lanes hit the same/adjacent h16 rows ->
// near-coalesced gather), scatter-adds into 80 KB LDS acc (stride-5 pad),
// then writes each agg element exactly once. Block->XCD: graph g -> XCD g%8.
// fuse_ep=1: out = acc*nd[node] + b (final epilogue fused).
// ---------------------------------------------------------------------------
__global__ __launch_bounds__(1024) void gather_kernel(
    const __half* __restrict__ h, const unsigned int* __restrict__ epack,
    float* __restrict__ out, const float* __restrict__ nd,
    const float* __restrict__ b, int epg, int npg, int fuse_ep)
{
    __shared__ float acc[NPG * ASTR];   // 80 KB
    const int t = threadIdx.x;
    // inverse swizzle: blk -> (g, fb) with all 16 blocks of graph g on XCD g%8
    int blk = blockIdx.x;
    int xcd = blk & 7;
    int q   = blk >> 3;                 // 0..31
    int g   = xcd + ((q & 1) << 3);     // 0..15
    int fb  = q >> 1;                   // 0..15
    const int f0 = fb * FPB;
    const int ebase = g * epg;
    const int nbase = g * npg;

    for (int i = t; i < NPG * ASTR; i += 1024) acc[i] = 0.f;
    __syncthreads();

    const int sub  = t & 1;             // which half (2 feats) of the 4-feat slice
    const int pidx = t >> 1;            // edge-pair index 0..511
    const __half* hseg = h + (size_t)nbase * 64 + f0 + sub * 2;
    const int iters = (epg + 511) / 512;
    for (int it = 0; it < iters; ++it) {
        int e = it * 512 + pidx;
        if (e < epg) {
            unsigned int w = epack[ebase + e];
            int sloc = (int)(w & 0xffffu);
            int dloc = (int)(w >> 16);
            unsigned int u = *(const unsigned int*)(hseg + (size_t)sloc * 64);
            __half2 hh = *(__half2*)&u;
            float2 f = __half22float2(hh);
            unsafeAtomicAdd(&acc[dloc * ASTR + sub * 2    ], f.x);
            unsafeAtomicAdd(&acc[dloc * ASTR + sub * 2 + 1], f.y);
        }
    }
    __syncthreads();

    // writeout: npg nodes x 4 feats, each element exactly once
    for (int i = t; i < npg * FPB; i += 1024) {
        int n = i >> 2, ff = i & 3;
        float v = acc[n * ASTR + ff];
        if (fuse_ep) v = v * nd[nbase + n] + b[f0 + ff];
        out[(size_t)(nbase + n) * 64 + f0 + ff] = v;
    }
}

// ---------------------------------------------------------------------------
extern "C" void kernel_launch(void* const* d_in, const int* in_sizes, int n_in,
                              void* d_out, int out_size, void* d_ws, size_t ws_size,
                              hipStream_t stream)
{
    const float* x  = (const float*)d_in[0];
    const float* W1 = (const float*)d_in[1];
    const float* b1 = (const float*)d_in[2];
    const float* W2 = (const float*)d_in[3];
    const float* b2 = (const float*)d_in[4];
    const float* W3 = (const float*)d_in[5];
    const float* b3 = (const float*)d_in[6];
    const int*  src = (const int*)d_in[7];
    const int*  dst = (const int*)d_in[8];

    const int E = in_sizes[7];
    const int N = in_sizes[0] / DIM;
    const int epg = E / NG;
    const int npg = N / NG;
    const int chunk = epg / CPG;

    // ws layout: ns[N] | nd[N] | h16[N*64 halves] | aggA[N*64 f32] |
    //            epack[E u32] | hsub | dsub  (no aliasing; ws is large)
    float*        ns    = (float*)d_ws;
    float*        nd    = ns + N;
    __half*       h16   = (__half*)(nd + N);
    float*        aggA  = (float*)(h16 + (size_t)N * DIM);
    unsigned int* epack = (unsigned int*)(aggA + (size_t)N * DIM);
    int*          hsub  = (int*)(epack + E);
    int*          dsub  = hsub + (size_t)NG * CPG * npg;
    float*        outp  = (float*)d_out;

    b1_hist<<<NG * CPG, 256, 0, stream>>>(src, dst, hsub, dsub, chunk, npg);
    b2_scan<<<NG, 1024, 0, stream>>>(hsub, dsub, ns, nd, epg, npg);
    b3_fill<<<NG * CPG, 256, 0, stream>>>(src, dst, hsub, epack, chunk, npg);

    const int gemm_blocks = N / 32;
    const int swiz = (N == 65536 && npg == 4096) ? 1 : 0;

    gemm_kernel<<<gemm_blocks, 256, 0, stream>>>(x, W1, b1, ns, nd, h16, 0, swiz);
    gather_kernel<<<256, 1024, 0, stream>>>(h16, epack, aggA, nd, b3, epg, npg, 0);

    gemm_kernel<<<gemm_blocks, 256, 0, stream>>>(aggA, W2, b1, ns, nd, h16, 1, swiz);
    gather_kernel<<<256, 1024, 0, stream>>>(h16, epack, aggA, nd, b3, epg, npg, 0);

    gemm_kernel<<<gemm_blocks, 256, 0, stream>>>(aggA, W3, b2, ns, nd, h16, 1, swiz);
    gather_kernel<<<256, 1024, 0, stream>>>(h16, epack, outp, nd, b3, epg, npg, 1);
}